// Round 6
// baseline (1874.510 us; speedup 1.0000x reference)
//
#include <hip/hip_runtime.h>

// GraphConv: edge MLP (384->256->640, bf16 MFMA) + CSR-gather pool + obj MLP (256->256->128)
// Round 6: edge_mlp latency-hiding — Abuf/Hbuf union (LDS 32KB -> 5 blocks/CU),
// launch_bounds(256,4), explicit 2-deep B-fragment prefetch in GEMM2.

using f32x4 = __attribute__((ext_vector_type(4))) float;
using s16x8 = __attribute__((ext_vector_type(8))) short;
typedef unsigned short u16x8 __attribute__((ext_vector_type(8)));

static __device__ __forceinline__ unsigned short f2b(float f) {
    unsigned int u = __float_as_uint(f);
    unsigned int r = (u + 0x7fffu + ((u >> 16) & 1u)) >> 16;  // RNE f32->bf16
    return (unsigned short)r;
}

static __device__ __forceinline__ float b2f(unsigned short b) {
    return __uint_as_float(((unsigned)b) << 16);
}

static __device__ __forceinline__ unsigned swz(unsigned row, unsigned byteoff) {
    return byteoff ^ ((row & 7u) << 4);  // spread 8-row group across banks (G4)
}

// packed bf16x2 atomic add, device scope (fallback path only)
static __device__ __forceinline__ void atomic_pk_bf16(const unsigned short* addr, unsigned data) {
    asm volatile("global_atomic_pk_add_bf16 %0, %1, off sc1"
                 :: "v"((unsigned long long)addr), "v"(data));
}

// ---------------- weight transpose + bf16 convert ----------------
__global__ void prep_weights(const float* __restrict__ w1a, const float* __restrict__ w1b,
                             const float* __restrict__ w2a, const float* __restrict__ w2b,
                             unsigned short* __restrict__ w1aT, unsigned short* __restrict__ w1bT,
                             unsigned short* __restrict__ w2aT, unsigned short* __restrict__ w2bT) {
    int t = blockIdx.x * blockDim.x + threadIdx.x;
    if (t < 256 * 384) { int n = t / 384, k = t % 384; w1aT[t] = f2b(w1a[(long long)k * 256 + n]); return; }
    t -= 256 * 384;
    if (t < 640 * 256) { int n = t / 256, k = t % 256; w1bT[t] = f2b(w1b[(long long)k * 640 + n]); return; }
    t -= 640 * 256;
    if (t < 256 * 256) { int n = t / 256, k = t % 256; w2aT[t] = f2b(w2a[(long long)k * 256 + n]); return; }
    t -= 256 * 256;
    if (t < 128 * 256) { int n = t / 256, k = t % 256; w2bT[t] = f2b(w2b[(long long)k * 128 + n]); return; }
}

// ---------------- CSR build ----------------
__global__ void count_kernel_i(const int* __restrict__ edges, int* __restrict__ cnt, int T) {
    int e = blockIdx.x * blockDim.x + threadIdx.x;
    if (e < T) {
        atomicAdd(&cnt[edges[2 * (long long)e]], 1);
        atomicAdd(&cnt[edges[2 * (long long)e + 1]], 1);
    }
}

// single-block exclusive scan of cnt[O] -> rowptr[O+1], cursor[O]
__global__ void scan_kernel(const int* __restrict__ cnt, int* __restrict__ rowptr,
                            int* __restrict__ cursor, int O) {
    __shared__ int sc[1024];
    const int tid = threadIdx.x;
    const int per = (O + 1023) >> 10;
    const int base = tid * per;
    int s = 0;
    for (int i = 0; i < per; ++i) { int j = base + i; if (j < O) s += cnt[j]; }
    sc[tid] = s;
    __syncthreads();
    for (int d = 1; d < 1024; d <<= 1) {
        int v = (tid >= d) ? sc[tid - d] : 0;
        __syncthreads();
        sc[tid] += v;
        __syncthreads();
    }
    int off = sc[tid] - s;  // exclusive prefix of this thread's chunk
    for (int i = 0; i < per; ++i) {
        int j = base + i;
        if (j < O) { rowptr[j] = off; cursor[j] = off; off += cnt[j]; }
    }
    if (tid == 0) rowptr[O] = sc[1023];
}

// s-side rowid = e, o-side rowid = T + e
__global__ void fill_kernel(const int* __restrict__ edges, int* __restrict__ cursor,
                            int* __restrict__ csr, int T) {
    int e = blockIdx.x * blockDim.x + threadIdx.x;
    if (e < T) {
        int s = edges[2 * (long long)e];
        int o = edges[2 * (long long)e + 1];
        int ps = atomicAdd(&cursor[s], 1); csr[ps] = e;
        int po = atomicAdd(&cursor[o], 1); csr[po] = T + e;
    }
}

// ---------------- edge MLP ----------------
// SCATTER=false: outSO = edgeout[2T][256] bf16, plain stores. SCATTER=true: outSO = pooled, pk atomics.
template<bool SCATTER>
__global__ __launch_bounds__(256, 4) void edge_mlp(
    const float* __restrict__ obj, const float* __restrict__ pred,
    const int* __restrict__ edges,
    const unsigned short* __restrict__ w1aT, const float* __restrict__ b1a,
    const unsigned short* __restrict__ w1bT, const float* __restrict__ b1b,
    unsigned short* __restrict__ outSO, float* __restrict__ outP, int T) {
    const int m0 = blockIdx.x * 64;
    const int tid = threadIdx.x;
    const int lane = tid & 63, wid = tid >> 6;
    const int wm = wid >> 1, wn = wid & 1;
    const bool evenL = ((lane & 1) == 0);

    // union: GEMM1 A-tile (64x128 bf16 = 16KB, row stride 256B) and H-tile
    // (64x256 bf16 = 32KB, row stride 512B). A dead before H written (barrier-protected).
    __shared__ unsigned short Ubuf[64 * 256];   // 32 KB
    unsigned short* Abuf = Ubuf;
    unsigned short* Hbuf = Ubuf;

    bool okR[2][4]; int sIdxR[2][4], oIdxR[2][4];
    #pragma unroll
    for (int mi = 0; mi < 2; ++mi)
        #pragma unroll
        for (int rr = 0; rr < 4; ++rr) {
            int row = wm * 32 + mi * 16 + ((lane >> 4) << 2) + rr;
            int e = m0 + row;
            okR[mi][rr] = e < T;
            if constexpr (SCATTER) {
                int ec = e < T ? e : T - 1;
                sIdxR[mi][rr] = edges[2 * (long long)ec];
                oIdxR[mi][rr] = edges[2 * (long long)ec + 1];
            }
        }

    const int r = tid >> 2;   // staging row 0..63
    const int q = tid & 3;
    int e_r = m0 + r; if (e_r >= T) e_r = T - 1;
    const int sIdx_r = edges[2 * (long long)e_r];
    const int oIdx_r = edges[2 * (long long)e_r + 1];

    f32x4 acc1[2][2][4];  // [nhalf][mi][nj]
    #pragma unroll
    for (int a = 0; a < 2; ++a)
        #pragma unroll
        for (int b = 0; b < 2; ++b)
            #pragma unroll
            for (int c = 0; c < 4; ++c) acc1[a][b][c] = f32x4{0.f, 0.f, 0.f, 0.f};

    // ---- GEMM1: [64,384] x [384,256], K in 3 blocks of 128 ----
    for (int kb = 0; kb < 3; ++kb) {
        const float* src;
        if (kb == 0)      src = obj + (long long)sIdx_r * 128;
        else if (kb == 1) src = pred + (long long)e_r * 128;
        else              src = obj + (long long)oIdx_r * 128;
        const float4* s4 = (const float4*)src;
        #pragma unroll
        for (int i = 0; i < 8; ++i) {
            float4 v = s4[q * 8 + i];
            ushort4 pk; pk.x = f2b(v.x); pk.y = f2b(v.y); pk.z = f2b(v.z); pk.w = f2b(v.w);
            unsigned byte = r * 256u + (q * 32u + i * 4u) * 2u;
            *(ushort4*)((char*)Abuf + swz(r, byte)) = pk;
        }
        __syncthreads();

        #pragma unroll
        for (int ks = 0; ks < 4; ++ks) {
            const int klane = ks * 32 + ((lane >> 4) << 3);
            s16x8 af[2];
            #pragma unroll
            for (int mi = 0; mi < 2; ++mi) {
                int row = wm * 32 + mi * 16 + (lane & 15);
                af[mi] = *(const s16x8*)((const char*)Abuf + swz(row, row * 256u + klane * 2u));
            }
            const int gk = kb * 128 + klane;
            #pragma unroll
            for (int nb = 0; nb < 2; ++nb)
                #pragma unroll
                for (int nj = 0; nj < 4; ++nj) {
                    int col = nb * 128 + wn * 64 + nj * 16 + (lane & 15);
                    s16x8 bf = *(const s16x8*)(w1aT + (long long)col * 384 + gk);
                    #pragma unroll
                    for (int mi = 0; mi < 2; ++mi)
                        acc1[nb][mi][nj] = __builtin_amdgcn_mfma_f32_16x16x32_bf16(af[mi], bf, acc1[nb][mi][nj], 0, 0, 0);
                }
        }
        __syncthreads();   // also protects Abuf region before H overwrite (kb==2)
    }

    // ---- epilogue1: H = relu(acc1 + b1a) -> Hbuf (bf16) ----
    #pragma unroll
    for (int nb = 0; nb < 2; ++nb)
        #pragma unroll
        for (int nj = 0; nj < 4; ++nj) {
            int col = nb * 128 + wn * 64 + nj * 16 + (lane & 15);
            float bias = b1a[col];
            #pragma unroll
            for (int mi = 0; mi < 2; ++mi)
                #pragma unroll
                for (int rr = 0; rr < 4; ++rr) {
                    int row = wm * 32 + mi * 16 + ((lane >> 4) << 2) + rr;
                    float v = acc1[nb][mi][nj][rr] + bias;
                    v = v > 0.f ? v : 0.f;
                    *(unsigned short*)((char*)Hbuf + swz(row, row * 512u + col * 2u)) = f2b(v);
                }
        }
    __syncthreads();

    // ---- GEMM2: [64,256] x [256,640] in 5 N-chunks of 128, 2-deep B prefetch ----
    #pragma unroll
    for (int t5 = 0; t5 < 5; ++t5) {
        const int nc = SCATTER ? ((t5 == 0) ? 2 : (t5 <= 2 ? t5 - 1 : t5)) : t5;
        f32x4 acc2[2][4];
        #pragma unroll
        for (int b = 0; b < 2; ++b)
            #pragma unroll
            for (int c = 0; c < 4; ++c) acc2[b][c] = f32x4{0.f, 0.f, 0.f, 0.f};

        // per-lane B base for this nc chunk
        const unsigned short* bbase = w1bT
            + (size_t)(nc * 128 + wn * 64 + (lane & 15)) * 256 + ((lane >> 4) << 3);

        s16x8 b2[2][4];
        #pragma unroll
        for (int nj = 0; nj < 4; ++nj)
            b2[0][nj] = *(const s16x8*)(bbase + nj * 16 * 256);

        #pragma unroll
        for (int ks = 0; ks < 8; ++ks) {
            if (ks < 7) {
                #pragma unroll
                for (int nj = 0; nj < 4; ++nj)
                    b2[(ks + 1) & 1][nj] = *(const s16x8*)(bbase + nj * 16 * 256 + (ks + 1) * 32);
            }
            const int klane = ks * 32 + ((lane >> 4) << 3);
            s16x8 af[2];
            #pragma unroll
            for (int mi = 0; mi < 2; ++mi) {
                int row = wm * 32 + mi * 16 + (lane & 15);
                af[mi] = *(const s16x8*)((const char*)Hbuf + swz(row, row * 512u + klane * 2u));
            }
            #pragma unroll
            for (int nj = 0; nj < 4; ++nj)
                #pragma unroll
                for (int mi = 0; mi < 2; ++mi)
                    acc2[mi][nj] = __builtin_amdgcn_mfma_f32_16x16x32_bf16(af[mi], b2[ks & 1][nj], acc2[mi][nj], 0, 0, 0);
        }

        if (nc == 2) {
            // new_p: plain f32 stores
            #pragma unroll
            for (int nj = 0; nj < 4; ++nj) {
                int col = nc * 128 + wn * 64 + nj * 16 + (lane & 15);
                float bias = b1b[col];
                #pragma unroll
                for (int mi = 0; mi < 2; ++mi)
                    #pragma unroll
                    for (int rr = 0; rr < 4; ++rr) {
                        int row = wm * 32 + mi * 16 + ((lane >> 4) << 2) + rr;
                        if (okR[mi][rr]) {
                            float v = acc2[mi][nj][rr] + bias;
                            v = v > 0.f ? v : 0.f;
                            outP[(long long)(m0 + row) * 128 + (col - 256)] = v;
                        }
                    }
            }
        } else {
            // pack col-pairs (bf16x2) via lane-pair shfl; store (or atomic in fallback)
            #pragma unroll
            for (int nj = 0; nj < 4; ++nj) {
                int col = nc * 128 + wn * 64 + nj * 16 + (lane & 15);
                float bias = b1b[col];
                int pc = (nc < 2) ? col : (col - 384);
                int pcb = (lane & 1) ? (pc - 1) : pc;
                #pragma unroll
                for (int mi = 0; mi < 2; ++mi) {
                    float vv[4];
                    #pragma unroll
                    for (int rr = 0; rr < 4; ++rr) {
                        float v = acc2[mi][nj][rr] + bias;
                        vv[rr] = v > 0.f ? v : 0.f;
                    }
                    float nb0 = __shfl_xor(vv[0], 1);
                    float nb1 = __shfl_xor(vv[1], 1);
                    float nb2 = __shfl_xor(vv[2], 1);
                    float nb3 = __shfl_xor(vv[3], 1);
                    #pragma unroll
                    for (int k = 0; k < 2; ++k) {
                        float lo = evenL ? (k ? vv[1] : vv[0]) : (k ? nb3 : nb2);
                        float hi = evenL ? (k ? nb1 : nb0) : (k ? vv[3] : vv[2]);
                        int rsel = evenL ? k : 2 + k;
                        bool ok = okR[mi][rsel];
                        unsigned pk = ((unsigned)f2b(hi) << 16) | f2b(lo);
                        if constexpr (SCATTER) {
                            int idx = (nc < 2) ? sIdxR[mi][rsel] : oIdxR[mi][rsel];
                            if (ok) atomic_pk_bf16(outSO + (size_t)idx * 256 + pcb, pk);
                        } else {
                            int row = wm * 32 + mi * 16 + ((lane >> 4) << 2) + rsel;
                            size_t e = (size_t)(m0 + row);
                            size_t rid = (nc < 2) ? e : (size_t)T + e;
                            if (ok) *(unsigned*)(outSO + rid * 256 + pcb) = pk;
                        }
                    }
                }
            }
        }
    }
}

// ---------------- CSR gather: pooled[o] = mean of incident edgeout rows ----------------
__global__ __launch_bounds__(256, 4) void pool_gather(
    const unsigned short* __restrict__ edgeout, const int* __restrict__ rowptr,
    const int* __restrict__ csr, unsigned short* __restrict__ pooled, int O) {
    int w = blockIdx.x * 4 + (threadIdx.x >> 6);   // one wave per object
    if (w >= O) return;
    const int lane = threadIdx.x & 63;
    const int beg = rowptr[w], end = rowptr[w + 1];
    float ax = 0.f, ay = 0.f, az = 0.f, aw = 0.f;
    float bx = 0.f, by = 0.f, bz = 0.f, bw = 0.f;
    int i = beg;
    for (; i + 1 < end; i += 2) {
        int r0 = csr[i], r1 = csr[i + 1];
        ushort4 v0 = *(const ushort4*)(edgeout + (size_t)r0 * 256 + lane * 4);
        ushort4 v1 = *(const ushort4*)(edgeout + (size_t)r1 * 256 + lane * 4);
        ax += b2f(v0.x); ay += b2f(v0.y); az += b2f(v0.z); aw += b2f(v0.w);
        bx += b2f(v1.x); by += b2f(v1.y); bz += b2f(v1.z); bw += b2f(v1.w);
    }
    if (i < end) {
        int r0 = csr[i];
        ushort4 v0 = *(const ushort4*)(edgeout + (size_t)r0 * 256 + lane * 4);
        ax += b2f(v0.x); ay += b2f(v0.y); az += b2f(v0.z); aw += b2f(v0.w);
    }
    float inv = 1.f / fmaxf((float)(end - beg), 1.f);
    ushort4 o4;
    o4.x = f2b((ax + bx) * inv); o4.y = f2b((ay + by) * inv);
    o4.z = f2b((az + bz) * inv); o4.w = f2b((aw + bw) * inv);
    *(ushort4*)(pooled + (size_t)w * 256 + lane * 4) = o4;
}

// ---------------- object MLP ----------------
// PRENORM: pooled already averaged. else divide by cnt.
template<bool PRENORM>
__global__ __launch_bounds__(256, 2) void obj_mlp(
    const unsigned short* __restrict__ pooled, const int* __restrict__ cnt,
    const unsigned short* __restrict__ w2aT, const float* __restrict__ b2a,
    const unsigned short* __restrict__ w2bT, const float* __restrict__ b2b,
    float* __restrict__ outObj, int O) {
    const int m0 = blockIdx.x * 64;
    const int tid = threadIdx.x;
    const int lane = tid & 63, wid = tid >> 6;
    const int wm = wid >> 1, wn = wid & 1;

    __shared__ unsigned short Abuf[64 * 256];  // 32 KB, stride 512B, swizzled; reused for H

    {
        const int r = tid >> 2, q = tid & 3;
        int objc = m0 + r; if (objc >= O) objc = O - 1;
        float inv = 1.0f;
        if constexpr (!PRENORM) inv = 1.0f / fmaxf((float)cnt[objc], 1.0f);
        const u16x8* s8 = (const u16x8*)(pooled + (size_t)objc * 256);
        #pragma unroll
        for (int i = 0; i < 8; ++i) {
            u16x8 v = s8[q * 8 + i];
            u16x8 o;
            if constexpr (PRENORM) {
                o = v;
            } else {
                #pragma unroll
                for (int j = 0; j < 8; ++j) o[j] = f2b(b2f(v[j]) * inv);
            }
            unsigned byte = r * 512u + (q * 64u + i * 8u) * 2u;
            *(u16x8*)((char*)Abuf + swz(r, byte)) = o;
        }
    }
    __syncthreads();

    // GEMM A: [64,256] x [256,256]
    f32x4 acc1[2][2][4];
    #pragma unroll
    for (int a = 0; a < 2; ++a)
        #pragma unroll
        for (int b = 0; b < 2; ++b)
            #pragma unroll
            for (int c = 0; c < 4; ++c) acc1[a][b][c] = f32x4{0.f, 0.f, 0.f, 0.f};
    #pragma unroll
    for (int ks = 0; ks < 8; ++ks) {
        const int klane = ks * 32 + ((lane >> 4) << 3);
        s16x8 af[2];
        #pragma unroll
        for (int mi = 0; mi < 2; ++mi) {
            int row = wm * 32 + mi * 16 + (lane & 15);
            af[mi] = *(const s16x8*)((const char*)Abuf + swz(row, row * 512u + klane * 2u));
        }
        #pragma unroll
        for (int nb = 0; nb < 2; ++nb)
            #pragma unroll
            for (int nj = 0; nj < 4; ++nj) {
                int col = nb * 128 + wn * 64 + nj * 16 + (lane & 15);
                s16x8 bf = *(const s16x8*)(w2aT + (long long)col * 256 + klane);
                #pragma unroll
                for (int mi = 0; mi < 2; ++mi)
                    acc1[nb][mi][nj] = __builtin_amdgcn_mfma_f32_16x16x32_bf16(af[mi], bf, acc1[nb][mi][nj], 0, 0, 0);
            }
    }
    __syncthreads();

    // H = relu(acc1 + b2a) -> Abuf
    #pragma unroll
    for (int nb = 0; nb < 2; ++nb)
        #pragma unroll
        for (int nj = 0; nj < 4; ++nj) {
            int col = nb * 128 + wn * 64 + nj * 16 + (lane & 15);
            float bias = b2a[col];
            #pragma unroll
            for (int mi = 0; mi < 2; ++mi)
                #pragma unroll
                for (int rr = 0; rr < 4; ++rr) {
                    int row = wm * 32 + mi * 16 + ((lane >> 4) << 2) + rr;
                    float v = acc1[nb][mi][nj][rr] + bias;
                    v = v > 0.f ? v : 0.f;
                    *(unsigned short*)((char*)Abuf + swz(row, row * 512u + col * 2u)) = f2b(v);
                }
        }
    __syncthreads();

    // GEMM B: [64,256] x [256,128]
    f32x4 acc2[2][4];
    #pragma unroll
    for (int b = 0; b < 2; ++b)
        #pragma unroll
        for (int c = 0; c < 4; ++c) acc2[b][c] = f32x4{0.f, 0.f, 0.f, 0.f};
    #pragma unroll
    for (int ks = 0; ks < 8; ++ks) {
        const int klane = ks * 32 + ((lane >> 4) << 3);
        s16x8 af[2];
        #pragma unroll
        for (int mi = 0; mi < 2; ++mi) {
            int row = wm * 32 + mi * 16 + (lane & 15);
            af[mi] = *(const s16x8*)((const char*)Abuf + swz(row, row * 512u + klane * 2u));
        }
        #pragma unroll
        for (int nj = 0; nj < 4; ++nj) {
            int col = wn * 64 + nj * 16 + (lane & 15);
            s16x8 bf = *(const s16x8*)(w2bT + (long long)col * 256 + klane);
            #pragma unroll
            for (int mi = 0; mi < 2; ++mi)
                acc2[mi][nj] = __builtin_amdgcn_mfma_f32_16x16x32_bf16(af[mi], bf, acc2[mi][nj], 0, 0, 0);
        }
    }

    #pragma unroll
    for (int nj = 0; nj < 4; ++nj) {
        int col = wn * 64 + nj * 16 + (lane & 15);
        float bias = b2b[col];
        #pragma unroll
        for (int mi = 0; mi < 2; ++mi)
            #pragma unroll
            for (int rr = 0; rr < 4; ++rr) {
                int row = wm * 32 + mi * 16 + ((lane >> 4) << 2) + rr;
                int o = m0 + row;
                if (o < O) {
                    float v = acc2[mi][nj][rr] + bias;
                    v = v > 0.f ? v : 0.f;
                    outObj[(long long)o * 128 + col] = v;
                }
            }
    }
}

extern "C" void kernel_launch(void* const* d_in, const int* in_sizes, int n_in,
                              void* d_out, int out_size, void* d_ws, size_t ws_size,
                              hipStream_t stream) {
    const float* obj  = (const float*)d_in[0];
    const float* pred = (const float*)d_in[1];
    const int*   edges = (const int*)d_in[2];
    const float* w1a = (const float*)d_in[3];
    const float* b1a = (const float*)d_in[4];
    const float* w1b = (const float*)d_in[5];
    const float* b1b = (const float*)d_in[6];
    const float* w2a = (const float*)d_in[7];
    const float* b2a = (const float*)d_in[8];
    const float* w2b = (const float*)d_in[9];
    const float* b2b = (const float*)d_in[10];

    const int O = in_sizes[0] / 128;
    const int T = in_sizes[1] / 128;

    auto al = [](size_t x) { return (x + 255) & ~(size_t)255; };
    const size_t szEdgeout = (size_t)2 * T * 256 * 2;
    const size_t szPooled  = (size_t)O * 256 * 2;
    const size_t szCnt     = (size_t)O * 4;
    const size_t szRow     = (size_t)(O + 1) * 4;
    const size_t szCsr     = (size_t)2 * T * 4;
    const size_t szW       = (size_t)(256 * 384 + 640 * 256 + 256 * 256 + 128 * 256) * 2;
    const size_t need = al(szEdgeout) + al(szPooled) + al(szCnt) * 2 + al(szRow) + al(szCsr) + al(szW);

    char* ws = (char*)d_ws;
    float* outObj = (float*)d_out;
    float* outP   = (float*)d_out + (size_t)O * 128;
    const int prepElems = 256 * 384 + 640 * 256 + 256 * 256 + 128 * 256;

    if (ws_size >= need) {
        // ---- CSR gather path ----
        size_t off = 0;
        unsigned short* edgeout = (unsigned short*)(ws + off); off += al(szEdgeout);
        unsigned short* pooled  = (unsigned short*)(ws + off); off += al(szPooled);
        int* cnt    = (int*)(ws + off); off += al(szCnt);
        int* cursor = (int*)(ws + off); off += al(szCnt);
        int* rowptr = (int*)(ws + off); off += al(szRow);
        int* csr    = (int*)(ws + off); off += al(szCsr);
        unsigned short* w1aT = (unsigned short*)(ws + off); off += (size_t)256 * 384 * 2;
        unsigned short* w1bT = (unsigned short*)(ws + off); off += (size_t)640 * 256 * 2;
        unsigned short* w2aT = (unsigned short*)(ws + off); off += (size_t)256 * 256 * 2;
        unsigned short* w2bT = (unsigned short*)(ws + off);

        hipMemsetAsync(cnt, 0, szCnt, stream);
        prep_weights<<<(prepElems + 255) / 256, 256, 0, stream>>>(w1a, w1b, w2a, w2b, w1aT, w1bT, w2aT, w2bT);
        count_kernel_i<<<(T + 255) / 256, 256, 0, stream>>>(edges, cnt, T);
        scan_kernel<<<1, 1024, 0, stream>>>(cnt, rowptr, cursor, O);
        fill_kernel<<<(T + 255) / 256, 256, 0, stream>>>(edges, cursor, csr, T);
        edge_mlp<false><<<(T + 63) / 64, 256, 0, stream>>>(obj, pred, edges, w1aT, b1a, w1bT, b1b, edgeout, outP, T);
        pool_gather<<<(O + 3) / 4, 256, 0, stream>>>(edgeout, rowptr, csr, pooled, O);
        obj_mlp<true><<<(O + 63) / 64, 256, 0, stream>>>(pooled, nullptr, w2aT, b2a, w2bT, b2b, outObj, O);
    } else {
        // ---- fallback: round-3 atomic scatter path ----
        size_t off = 0;
        unsigned short* pooled = (unsigned short*)(ws + off); off += szPooled;
        int* cnt = (int*)(ws + off); off += al(szCnt);
        unsigned short* w1aT = (unsigned short*)(ws + off); off += (size_t)256 * 384 * 2;
        unsigned short* w1bT = (unsigned short*)(ws + off); off += (size_t)640 * 256 * 2;
        unsigned short* w2aT = (unsigned short*)(ws + off); off += (size_t)256 * 256 * 2;
        unsigned short* w2bT = (unsigned short*)(ws + off);

        hipMemsetAsync(pooled, 0, szPooled + szCnt, stream);
        prep_weights<<<(prepElems + 255) / 256, 256, 0, stream>>>(w1a, w1b, w2a, w2b, w1aT, w1bT, w2aT, w2bT);
        count_kernel_i<<<(T + 255) / 256, 256, 0, stream>>>(edges, cnt, T);
        edge_mlp<true><<<(T + 63) / 64, 256, 0, stream>>>(obj, pred, edges, w1aT, b1a, w1bT, b1b, pooled, outP, T);
        obj_mlp<false><<<(O + 63) / 64, 256, 0, stream>>>(pooled, cnt, w2aT, b2a, w2bT, b2b, outObj, O);
    }
}

// Round 7
// 956.609 us; speedup vs baseline: 1.9595x; 1.9595x over previous
//
#include <hip/hip_runtime.h>

// GraphConv: edge MLP (384->256->640, bf16 MFMA) + CSR-gather pool + obj MLP (256->256->128)
// Round 7: edge_mlp weights staged through LDS (m90/m97 pattern): prep_weights emits
// XOR-pre-swizzled 16KB tiles [128c][64k]; kernel stages via global_load_lds (linear dest),
// MFMA feeds from swizzled ds_read_b128. 2-barrier stages, 48KB LDS, 3 blocks/CU.

using f32x4 = __attribute__((ext_vector_type(4))) float;
using s16x8 = __attribute__((ext_vector_type(8))) short;
typedef unsigned short u16x8 __attribute__((ext_vector_type(8)));

static __device__ __forceinline__ unsigned short f2b(float f) {
    unsigned int u = __float_as_uint(f);
    unsigned int r = (u + 0x7fffu + ((u >> 16) & 1u)) >> 16;  // RNE f32->bf16
    return (unsigned short)r;
}

static __device__ __forceinline__ float b2f(unsigned short b) {
    return __uint_as_float(((unsigned)b) << 16);
}

static __device__ __forceinline__ unsigned swz(unsigned row, unsigned byteoff) {
    return byteoff ^ ((row & 7u) << 4);  // spread 8-row group across banks (G4)
}

// async global->LDS, 16B per lane: global src is PER-LANE, lds dst is wave-uniform base
// (hw adds lane*16) — rule #21: dest is linear, source holds the pre-swizzled layout.
static __device__ __forceinline__ void gload_lds16(const unsigned short* g, unsigned short* l) {
    __builtin_amdgcn_global_load_lds(
        (const __attribute__((address_space(1))) unsigned int*)g,
        (__attribute__((address_space(3))) unsigned int*)l,
        16, 0, 0);
}

// ---------------- weight prep: bf16 + tiling + pre-swizzle ----------------
// w1a -> 12 tiles (nc1*6+kt), w1b -> 20 tiles (nc*4+kt2); each tile [128c][64k] bf16,
// element (c,kk) at byte (c*128 + kk*2) ^ ((c&7)<<4). w2a/w2b: plain [n][k] transpose.
__global__ void prep_weights(const float* __restrict__ w1a, const float* __restrict__ w1b,
                             const float* __restrict__ w2a, const float* __restrict__ w2b,
                             unsigned short* __restrict__ w1aT, unsigned short* __restrict__ w1bT,
                             unsigned short* __restrict__ w2aT, unsigned short* __restrict__ w2bT) {
    int t = blockIdx.x * blockDim.x + threadIdx.x;
    if (t < 2 * 6 * 8192) {
        int tile = t >> 13; int nc1 = tile / 6, kt = tile % 6;
        int rem = t & 8191; int c = rem >> 6, kk = rem & 63;
        unsigned byte = ((unsigned)(c * 128 + kk * 2)) ^ ((c & 7u) << 4);
        *(unsigned short*)((char*)w1aT + (size_t)tile * 16384 + byte) =
            f2b(w1a[(size_t)(kt * 64 + kk) * 256 + nc1 * 128 + c]);
        return;
    }
    t -= 98304;
    if (t < 5 * 4 * 8192) {
        int tile = t >> 13; int nc = tile >> 2, kt2 = tile & 3;
        int rem = t & 8191; int c = rem >> 6, kk = rem & 63;
        unsigned byte = ((unsigned)(c * 128 + kk * 2)) ^ ((c & 7u) << 4);
        *(unsigned short*)((char*)w1bT + (size_t)tile * 16384 + byte) =
            f2b(w1b[(size_t)(kt2 * 64 + kk) * 640 + nc * 128 + c]);
        return;
    }
    t -= 163840;
    if (t < 65536) { int n = t >> 8, k = t & 255; w2aT[t] = f2b(w2a[k * 256 + n]); return; }
    t -= 65536;
    if (t < 32768) { int n = t >> 8, k = t & 255; w2bT[t] = f2b(w2b[k * 128 + n]); return; }
}

// ---------------- CSR build ----------------
__global__ void count_kernel_i(const int* __restrict__ edges, int* __restrict__ cnt, int T) {
    int e = blockIdx.x * blockDim.x + threadIdx.x;
    if (e < T) {
        atomicAdd(&cnt[edges[2 * (long long)e]], 1);
        atomicAdd(&cnt[edges[2 * (long long)e + 1]], 1);
    }
}

__global__ void scan_kernel(const int* __restrict__ cnt, int* __restrict__ rowptr,
                            int* __restrict__ cursor, int O) {
    __shared__ int sc[1024];
    const int tid = threadIdx.x;
    const int per = (O + 1023) >> 10;
    const int base = tid * per;
    int s = 0;
    for (int i = 0; i < per; ++i) { int j = base + i; if (j < O) s += cnt[j]; }
    sc[tid] = s;
    __syncthreads();
    for (int d = 1; d < 1024; d <<= 1) {
        int v = (tid >= d) ? sc[tid - d] : 0;
        __syncthreads();
        sc[tid] += v;
        __syncthreads();
    }
    int off = sc[tid] - s;
    for (int i = 0; i < per; ++i) {
        int j = base + i;
        if (j < O) { rowptr[j] = off; cursor[j] = off; off += cnt[j]; }
    }
    if (tid == 0) rowptr[O] = sc[1023];
}

__global__ void fill_kernel(const int* __restrict__ edges, int* __restrict__ cursor,
                            int* __restrict__ csr, int T) {
    int e = blockIdx.x * blockDim.x + threadIdx.x;
    if (e < T) {
        int s = edges[2 * (long long)e];
        int o = edges[2 * (long long)e + 1];
        int ps = atomicAdd(&cursor[s], 1); csr[ps] = e;
        int po = atomicAdd(&cursor[o], 1); csr[po] = T + e;
    }
}

// ---------------- edge MLP, LDS-staged weights ----------------
__global__ __launch_bounds__(256, 3) void edge_mlp(
    const float* __restrict__ obj, const float* __restrict__ pred,
    const int* __restrict__ edges,
    const unsigned short* __restrict__ w1aT, const float* __restrict__ b1a,
    const unsigned short* __restrict__ w1bT, const float* __restrict__ b1b,
    unsigned short* __restrict__ edgeout, float* __restrict__ outP, int T) {
    const int m0 = blockIdx.x * 64;
    const int tid = threadIdx.x;
    const int lane = tid & 63, wid = tid >> 6;
    const int wm = wid >> 1, wn = wid & 1;
    const bool evenL = ((lane & 1) == 0);

    __shared__ unsigned short Hbuf[64 * 256];  // 32 KB: GEMM1 A-slice (first 8KB) then H
    __shared__ unsigned short Bbuf[8192];      // 16 KB: one B tile [128c][64k]
    unsigned short* Abuf = Hbuf;               // union: A dead before H written

    bool okR[2][4];
    #pragma unroll
    for (int mi = 0; mi < 2; ++mi)
        #pragma unroll
        for (int rr = 0; rr < 4; ++rr)
            okR[mi][rr] = (m0 + wm * 32 + mi * 16 + ((lane >> 4) << 2) + rr) < T;

    const int r = tid >> 2;   // staging row 0..63
    const int q = tid & 3;
    int e_r = m0 + r; if (e_r >= T) e_r = T - 1;
    const int sIdx_r = edges[2 * (long long)e_r];
    const int oIdx_r = edges[2 * (long long)e_r + 1];

    f32x4 acc1[2][2][4];  // [nc1][mi][nj]
    #pragma unroll
    for (int a = 0; a < 2; ++a)
        #pragma unroll
        for (int b = 0; b < 2; ++b)
            #pragma unroll
            for (int c = 0; c < 4; ++c) acc1[a][b][c] = f32x4{0.f, 0.f, 0.f, 0.f};

    // ---- GEMM1: [64,384]x[384,256] as 6 kt-stages (64k) x 2 col-halves ----
    for (int kt = 0; kt < 6; ++kt) {
        // gather A slice: row r, k = kt*64..+63 (f32) -> bf16 -> swizzled LDS
        {
            const float* src;
            if (kt < 2)      src = obj  + (long long)sIdx_r * 128 + kt * 64;
            else if (kt < 4) src = pred + (long long)e_r   * 128 + (kt - 2) * 64;
            else             src = obj  + (long long)oIdx_r * 128 + (kt - 4) * 64;
            const float4* s4 = (const float4*)src;
            #pragma unroll
            for (int i = 0; i < 4; ++i) {
                float4 v = s4[q * 4 + i];
                ushort4 pk; pk.x = f2b(v.x); pk.y = f2b(v.y); pk.z = f2b(v.z); pk.w = f2b(v.w);
                unsigned byte = (r * 128u + q * 32u + i * 8u) ^ ((r & 7u) << 4);
                *(ushort4*)((char*)Abuf + byte) = pk;
            }
        }
        #pragma unroll
        for (int nc1 = 0; nc1 < 2; ++nc1) {
            // stage B tile (nc1,kt): 16KB, 4 chunks of 1KB per wave, linear DMA
            const unsigned short* gt = w1aT + (size_t)(nc1 * 6 + kt) * 8192;
            #pragma unroll
            for (int rr4 = 0; rr4 < 4; ++rr4) {
                unsigned off = wid * 4096u + rr4 * 1024u;
                gload_lds16((const unsigned short*)((const char*)gt + off + lane * 16u),
                            (unsigned short*)((char*)Bbuf + off));
            }
            __syncthreads();
            #pragma unroll
            for (int ks = 0; ks < 2; ++ks) {
                const unsigned kk = ks * 32u + ((lane >> 4) << 3);
                s16x8 af[2];
                #pragma unroll
                for (int mi = 0; mi < 2; ++mi) {
                    unsigned row = wm * 32u + mi * 16u + (lane & 15);
                    af[mi] = *(const s16x8*)((const char*)Abuf + ((row * 128u + kk * 2u) ^ ((row & 7u) << 4)));
                }
                #pragma unroll
                for (int nj = 0; nj < 4; ++nj) {
                    unsigned c = wn * 64u + nj * 16u + (lane & 15);
                    s16x8 bf = *(const s16x8*)((const char*)Bbuf + ((c * 128u + kk * 2u) ^ ((c & 7u) << 4)));
                    #pragma unroll
                    for (int mi = 0; mi < 2; ++mi)
                        acc1[nc1][mi][nj] = __builtin_amdgcn_mfma_f32_16x16x32_bf16(af[mi], bf, acc1[nc1][mi][nj], 0, 0, 0);
                }
            }
            __syncthreads();
        }
    }

    // ---- epilogue1: H = relu(acc1 + b1a) -> Hbuf (bf16, [64][256] swizzled) ----
    #pragma unroll
    for (int nb = 0; nb < 2; ++nb)
        #pragma unroll
        for (int nj = 0; nj < 4; ++nj) {
            int col = nb * 128 + wn * 64 + nj * 16 + (lane & 15);
            float bias = b1a[col];
            #pragma unroll
            for (int mi = 0; mi < 2; ++mi)
                #pragma unroll
                for (int rr = 0; rr < 4; ++rr) {
                    unsigned row = wm * 32u + mi * 16u + ((lane >> 4) << 2) + rr;
                    float v = acc1[nb][mi][nj][rr] + bias;
                    v = v > 0.f ? v : 0.f;
                    *(unsigned short*)((char*)Hbuf + swz(row, row * 512u + col * 2u)) = f2b(v);
                }
        }
    __syncthreads();

    // ---- GEMM2: [64,256]x[256,640] as 5 nc x 4 kt2-stages ----
    #pragma unroll
    for (int nc = 0; nc < 5; ++nc) {
        f32x4 acc2[2][4];
        #pragma unroll
        for (int b = 0; b < 2; ++b)
            #pragma unroll
            for (int c = 0; c < 4; ++c) acc2[b][c] = f32x4{0.f, 0.f, 0.f, 0.f};

        #pragma unroll
        for (int kt2 = 0; kt2 < 4; ++kt2) {
            const unsigned short* gt = w1bT + (size_t)(nc * 4 + kt2) * 8192;
            #pragma unroll
            for (int rr4 = 0; rr4 < 4; ++rr4) {
                unsigned off = wid * 4096u + rr4 * 1024u;
                gload_lds16((const unsigned short*)((const char*)gt + off + lane * 16u),
                            (unsigned short*)((char*)Bbuf + off));
            }
            __syncthreads();
            #pragma unroll
            for (int ks = 0; ks < 2; ++ks) {
                const unsigned kkB = ks * 32u + ((lane >> 4) << 3);        // within tile
                const unsigned kkH = kt2 * 64u + kkB;                      // within 256
                s16x8 af[2];
                #pragma unroll
                for (int mi = 0; mi < 2; ++mi) {
                    unsigned row = wm * 32u + mi * 16u + (lane & 15);
                    af[mi] = *(const s16x8*)((const char*)Hbuf + swz(row, row * 512u + kkH * 2u));
                }
                #pragma unroll
                for (int nj = 0; nj < 4; ++nj) {
                    unsigned c = wn * 64u + nj * 16u + (lane & 15);
                    s16x8 bf = *(const s16x8*)((const char*)Bbuf + ((c * 128u + kkB * 2u) ^ ((c & 7u) << 4)));
                    #pragma unroll
                    for (int mi = 0; mi < 2; ++mi)
                        acc2[mi][nj] = __builtin_amdgcn_mfma_f32_16x16x32_bf16(af[mi], bf, acc2[mi][nj], 0, 0, 0);
                }
            }
            __syncthreads();
        }

        // epilogue chunk nc
        if (nc == 2) {
            #pragma unroll
            for (int nj = 0; nj < 4; ++nj) {
                int col = nc * 128 + wn * 64 + nj * 16 + (lane & 15);
                float bias = b1b[col];
                #pragma unroll
                for (int mi = 0; mi < 2; ++mi)
                    #pragma unroll
                    for (int rr = 0; rr < 4; ++rr) {
                        int row = wm * 32 + mi * 16 + ((lane >> 4) << 2) + rr;
                        if (okR[mi][rr]) {
                            float v = acc2[mi][nj][rr] + bias;
                            v = v > 0.f ? v : 0.f;
                            outP[(long long)(m0 + row) * 128 + (col - 256)] = v;
                        }
                    }
            }
        } else {
            #pragma unroll
            for (int nj = 0; nj < 4; ++nj) {
                int col = nc * 128 + wn * 64 + nj * 16 + (lane & 15);
                float bias = b1b[col];
                int pc = (nc < 2) ? col : (col - 384);
                int pcb = (lane & 1) ? (pc - 1) : pc;
                #pragma unroll
                for (int mi = 0; mi < 2; ++mi) {
                    float vv[4];
                    #pragma unroll
                    for (int rr = 0; rr < 4; ++rr) {
                        float v = acc2[mi][nj][rr] + bias;
                        vv[rr] = v > 0.f ? v : 0.f;
                    }
                    float nb0 = __shfl_xor(vv[0], 1);
                    float nb1 = __shfl_xor(vv[1], 1);
                    float nb2 = __shfl_xor(vv[2], 1);
                    float nb3 = __shfl_xor(vv[3], 1);
                    #pragma unroll
                    for (int k = 0; k < 2; ++k) {
                        float lo = evenL ? (k ? vv[1] : vv[0]) : (k ? nb3 : nb2);
                        float hi = evenL ? (k ? nb1 : nb0) : (k ? vv[3] : vv[2]);
                        int rsel = evenL ? k : 2 + k;
                        if (okR[mi][rsel]) {
                            int row = wm * 32 + mi * 16 + ((lane >> 4) << 2) + rsel;
                            size_t e = (size_t)(m0 + row);
                            size_t rid = (nc < 2) ? e : (size_t)T + e;
                            unsigned pk = ((unsigned)f2b(hi) << 16) | f2b(lo);
                            *(unsigned*)(edgeout + rid * 256 + pcb) = pk;
                        }
                    }
                }
            }
        }
    }
}

// ---------------- CSR gather: pooled[o] = mean of incident edgeout rows ----------------
__global__ __launch_bounds__(256, 4) void pool_gather(
    const unsigned short* __restrict__ edgeout, const int* __restrict__ rowptr,
    const int* __restrict__ csr, unsigned short* __restrict__ pooled, int O) {
    int w = blockIdx.x * 4 + (threadIdx.x >> 6);
    if (w >= O) return;
    const int lane = threadIdx.x & 63;
    const int beg = rowptr[w], end = rowptr[w + 1];
    float ax = 0.f, ay = 0.f, az = 0.f, aw = 0.f;
    float bx = 0.f, by = 0.f, bz = 0.f, bw = 0.f;
    int i = beg;
    for (; i + 1 < end; i += 2) {
        int r0 = csr[i], r1 = csr[i + 1];
        ushort4 v0 = *(const ushort4*)(edgeout + (size_t)r0 * 256 + lane * 4);
        ushort4 v1 = *(const ushort4*)(edgeout + (size_t)r1 * 256 + lane * 4);
        ax += b2f(v0.x); ay += b2f(v0.y); az += b2f(v0.z); aw += b2f(v0.w);
        bx += b2f(v1.x); by += b2f(v1.y); bz += b2f(v1.z); bw += b2f(v1.w);
    }
    if (i < end) {
        int r0 = csr[i];
        ushort4 v0 = *(const ushort4*)(edgeout + (size_t)r0 * 256 + lane * 4);
        ax += b2f(v0.x); ay += b2f(v0.y); az += b2f(v0.z); aw += b2f(v0.w);
    }
    float inv = 1.f / fmaxf((float)(end - beg), 1.f);
    ushort4 o4;
    o4.x = f2b((ax + bx) * inv); o4.y = f2b((ay + by) * inv);
    o4.z = f2b((az + bz) * inv); o4.w = f2b((aw + bw) * inv);
    *(ushort4*)(pooled + (size_t)w * 256 + lane * 4) = o4;
}

// ---------------- object MLP (pooled pre-normalized) ----------------
__global__ __launch_bounds__(256, 2) void obj_mlp(
    const unsigned short* __restrict__ pooled,
    const unsigned short* __restrict__ w2aT, const float* __restrict__ b2a,
    const unsigned short* __restrict__ w2bT, const float* __restrict__ b2b,
    float* __restrict__ outObj, int O) {
    const int m0 = blockIdx.x * 64;
    const int tid = threadIdx.x;
    const int lane = tid & 63, wid = tid >> 6;
    const int wm = wid >> 1, wn = wid & 1;

    __shared__ unsigned short Abuf[64 * 256];

    {
        const int r = tid >> 2, q = tid & 3;
        int objc = m0 + r; if (objc >= O) objc = O - 1;
        const u16x8* s8 = (const u16x8*)(pooled + (size_t)objc * 256);
        #pragma unroll
        for (int i = 0; i < 8; ++i) {
            u16x8 v = s8[q * 8 + i];
            unsigned byte = r * 512u + (q * 64u + i * 8u) * 2u;
            *(u16x8*)((char*)Abuf + swz(r, byte)) = v;
        }
    }
    __syncthreads();

    f32x4 acc1[2][2][4];
    #pragma unroll
    for (int a = 0; a < 2; ++a)
        #pragma unroll
        for (int b = 0; b < 2; ++b)
            #pragma unroll
            for (int c = 0; c < 4; ++c) acc1[a][b][c] = f32x4{0.f, 0.f, 0.f, 0.f};
    #pragma unroll
    for (int ks = 0; ks < 8; ++ks) {
        const int klane = ks * 32 + ((lane >> 4) << 3);
        s16x8 af[2];
        #pragma unroll
        for (int mi = 0; mi < 2; ++mi) {
            int row = wm * 32 + mi * 16 + (lane & 15);
            af[mi] = *(const s16x8*)((const char*)Abuf + swz(row, row * 512u + klane * 2u));
        }
        #pragma unroll
        for (int nb = 0; nb < 2; ++nb)
            #pragma unroll
            for (int nj = 0; nj < 4; ++nj) {
                int col = nb * 128 + wn * 64 + nj * 16 + (lane & 15);
                s16x8 bf = *(const s16x8*)(w2aT + (long long)col * 256 + klane);
                #pragma unroll
                for (int mi = 0; mi < 2; ++mi)
                    acc1[nb][mi][nj] = __builtin_amdgcn_mfma_f32_16x16x32_bf16(af[mi], bf, acc1[nb][mi][nj], 0, 0, 0);
            }
    }
    __syncthreads();

    #pragma unroll
    for (int nb = 0; nb < 2; ++nb)
        #pragma unroll
        for (int nj = 0; nj < 4; ++nj) {
            int col = nb * 128 + wn * 64 + nj * 16 + (lane & 15);
            float bias = b2a[col];
            #pragma unroll
            for (int mi = 0; mi < 2; ++mi)
                #pragma unroll
                for (int rr = 0; rr < 4; ++rr) {
                    int row = wm * 32 + mi * 16 + ((lane >> 4) << 2) + rr;
                    float v = acc1[nb][mi][nj][rr] + bias;
                    v = v > 0.f ? v : 0.f;
                    *(unsigned short*)((char*)Abuf + swz(row, row * 512u + col * 2u)) = f2b(v);
                }
        }
    __syncthreads();

    f32x4 acc2[2][4];
    #pragma unroll
    for (int b = 0; b < 2; ++b)
        #pragma unroll
        for (int c = 0; c < 4; ++c) acc2[b][c] = f32x4{0.f, 0.f, 0.f, 0.f};
    #pragma unroll
    for (int ks = 0; ks < 8; ++ks) {
        const int klane = ks * 32 + ((lane >> 4) << 3);
        s16x8 af[2];
        #pragma unroll
        for (int mi = 0; mi < 2; ++mi) {
            int row = wm * 32 + mi * 16 + (lane & 15);
            af[mi] = *(const s16x8*)((const char*)Abuf + swz(row, row * 512u + klane * 2u));
        }
        #pragma unroll
        for (int nj = 0; nj < 4; ++nj) {
            int col = wn * 64 + nj * 16 + (lane & 15);
            s16x8 bf = *(const s16x8*)(w2bT + (long long)col * 256 + klane);
            #pragma unroll
            for (int mi = 0; mi < 2; ++mi)
                acc2[mi][nj] = __builtin_amdgcn_mfma_f32_16x16x32_bf16(af[mi], bf, acc2[mi][nj], 0, 0, 0);
        }
    }

    #pragma unroll
    for (int nj = 0; nj < 4; ++nj) {
        int col = wn * 64 + nj * 16 + (lane & 15);
        float bias = b2b[col];
        #pragma unroll
        for (int mi = 0; mi < 2; ++mi)
            #pragma unroll
            for (int rr = 0; rr < 4; ++rr) {
                int row = wm * 32 + mi * 16 + ((lane >> 4) << 2) + rr;
                int o = m0 + row;
                if (o < O) {
                    float v = acc2[mi][nj][rr] + bias;
                    v = v > 0.f ? v : 0.f;
                    outObj[(long long)o * 128 + col] = v;
                }
            }
    }
}

extern "C" void kernel_launch(void* const* d_in, const int* in_sizes, int n_in,
                              void* d_out, int out_size, void* d_ws, size_t ws_size,
                              hipStream_t stream) {
    const float* obj  = (const float*)d_in[0];
    const float* pred = (const float*)d_in[1];
    const int*   edges = (const int*)d_in[2];
    const float* w1a = (const float*)d_in[3];
    const float* b1a = (const float*)d_in[4];
    const float* w1b = (const float*)d_in[5];
    const float* b1b = (const float*)d_in[6];
    const float* w2a = (const float*)d_in[7];
    const float* b2a = (const float*)d_in[8];
    const float* w2b = (const float*)d_in[9];
    const float* b2b = (const float*)d_in[10];

    const int O = in_sizes[0] / 128;
    const int T = in_sizes[1] / 128;

    auto al = [](size_t x) { return (x + 255) & ~(size_t)255; };
    const size_t szEdgeout = (size_t)2 * T * 256 * 2;
    const size_t szPooled  = (size_t)O * 256 * 2;
    const size_t szCnt     = (size_t)O * 4;
    const size_t szRow     = (size_t)(O + 1) * 4;
    const size_t szCsr     = (size_t)2 * T * 4;

    size_t off = 0;
    char* ws = (char*)d_ws;
    unsigned short* edgeout = (unsigned short*)(ws + off); off += al(szEdgeout);
    unsigned short* pooled  = (unsigned short*)(ws + off); off += al(szPooled);
    int* cnt    = (int*)(ws + off); off += al(szCnt);
    int* cursor = (int*)(ws + off); off += al(szCnt);
    int* rowptr = (int*)(ws + off); off += al(szRow);
    int* csr    = (int*)(ws + off); off += al(szCsr);
    unsigned short* w1aT = (unsigned short*)(ws + off); off += (size_t)12 * 8192 * 2;   // 192 KB tiled
    unsigned short* w1bT = (unsigned short*)(ws + off); off += (size_t)20 * 8192 * 2;   // 320 KB tiled
    unsigned short* w2aT = (unsigned short*)(ws + off); off += (size_t)256 * 256 * 2;
    unsigned short* w2bT = (unsigned short*)(ws + off);

    float* outObj = (float*)d_out;
    float* outP   = (float*)d_out + (size_t)O * 128;

    hipMemsetAsync(cnt, 0, szCnt, stream);
    const int prepElems = 98304 + 163840 + 65536 + 32768;
    prep_weights<<<(prepElems + 255) / 256, 256, 0, stream>>>(w1a, w1b, w2a, w2b, w1aT, w1bT, w2aT, w2bT);
    count_kernel_i<<<(T + 255) / 256, 256, 0, stream>>>(edges, cnt, T);
    scan_kernel<<<1, 1024, 0, stream>>>(cnt, rowptr, cursor, O);
    fill_kernel<<<(T + 255) / 256, 256, 0, stream>>>(edges, cursor, csr, T);
    edge_mlp<<<(T + 63) / 64, 256, 0, stream>>>(obj, pred, edges, w1aT, b1a, w1bT, b1b, edgeout, outP, T);
    pool_gather<<<(O + 3) / 4, 256, 0, stream>>>(edgeout, rowptr, csr, pooled, O);
    obj_mlp<<<(O + 63) / 64, 256, 0, stream>>>(pooled, w2aT, b2a, w2bT, b2b, outObj, O);
}